// Round 1
// baseline (110.212 us; speedup 1.0000x reference)
//
#include <hip/hip_runtime.h>
#include <hip/hip_bf16.h>
#include <hip/hip_fp16.h>

// ESN cell update, MI355X. B=512, D=256, N=8192, NNZ=134217.
//
// 3-dispatch pipeline:
//   1. hipMemsetAsync: zero per-column counters (32 KB)
//   2. prep_k: state [B,N] f32 -> stateTh [N,B] fp16 (b-pairs packed in uint),
//      inputs -> inputsT f32, COO scatter into per-column buckets with the
//      value pre-duplicated as half2{v,v} and the row PRE-SHIFTED to a byte
//      offset (row<<10) so the gather loop needs a single v_add for the addr.
//   3. spmm_k v2: grid = (N/16 col-tiles) x 2 batch-slices of 256 b.
//      slice = blockIdx&1 -> even/odd XCDs (round-robin): each XCD's gather
//      working set is a 4 MB fp16 b-slice == its private L2.
//      8 waves/block; each wave owns 2 columns SEQUENTIALLY with EXACT
//      per-column loop bounds (no max-of-4 padding). Per 2 nnz: one
//      ds_read_b128 (software-prefetched, uniform broadcast) + 2 v_add +
//      2 global_load_dwordx2 (4 batch elems/lane) + 4 v_pk_fma_f16.
//      Epilogue per col: win + fast-tanh + leaky integrate for 4 b's/lane,
//      LDS reshuffle, 64-B-per-thread-pair coalesced row-major out.
//
// Precision: fp16 state (10-bit mantissa), fp16 dup'd vals, fp16 accumulate
// over ~16 terms ~1e-3 abs. Threshold 1.8e-2; measured absmax ~0.004.

#define ESN_B 512
#define ESN_D 256
#define ESN_N 8192
#define ESN_ALPHA 0.9f
#define CAP  128   // global bucket capacity per column
#define LCAP 64    // LDS-staged capacity (max nnz/col ~45 at Poisson(16.4))
#define GS   16    // columns per spmm block
#define NSL  2     // batch slices (256 b each, 4 MB fp16 per slice == L2/XCD)

__device__ __forceinline__ unsigned pack_h2(float lo, float hi) {
    return (unsigned)__half_as_ushort(__float2half(lo)) |
           ((unsigned)__half_as_ushort(__float2half(hi)) << 16);
}

__device__ __forceinline__ __half2 int_as_h2(int u) {
    union { int i; __half2 h; } c; c.i = u; return c.h;
}

__device__ __forceinline__ float fast_tanh(float x) {
    x = fminf(fmaxf(x, -9.0f), 9.0f);
    const float e = __expf(2.0f * x);
    return (e - 1.0f) * __builtin_amdgcn_rcpf(e + 1.0f);
}

__global__ __launch_bounds__(256) void prep_k(const float* __restrict__ state,
                                              const float* __restrict__ inputs,
                                              const int* __restrict__ wres_rows,
                                              const int* __restrict__ wres_cols,
                                              const float* __restrict__ wres_vals,
                                              int* __restrict__ cnt,
                                              int2* __restrict__ bucket,
                                              unsigned* __restrict__ stateTh,
                                              float* __restrict__ inputsT,
                                              int nnz) {
    __shared__ unsigned utile[64][33];   // [n-col][b-pair] packed fp16x2
    __shared__ float    tile2[32][33];
    const int t = blockIdx.x;
    const int tid = threadIdx.x;
    const int NB_TS = (ESN_N / 64) * (ESN_B / 64);  // 1024 state tiles (64x64)
    const int NB_TI = (ESN_D / 32) * (ESN_B / 32);  // 128 input tiles

    if (t < NB_TS) {
        // state [512, 8192] f32 -> stateTh [8192, 256] uint (fp16 b-pairs)
        const int bx = t & 127, by = t >> 7;        // N/64 = 128 tiles in x
        const int c0 = bx * 64, r0 = by * 64;
        const int x = tid & 15, yp = tid >> 4;      // x: float4-col, yp: b-pair
#pragma unroll
        for (int i = 0; i < 2; ++i) {
            const int ypi = yp + 16 * i;            // b-pair 0..31
            const float4 v0 = *(const float4*)(state + (size_t)(r0 + 2 * ypi) * ESN_N + c0 + 4 * x);
            const float4 v1 = *(const float4*)(state + (size_t)(r0 + 2 * ypi + 1) * ESN_N + c0 + 4 * x);
            utile[4 * x + 0][ypi] = pack_h2(v0.x, v1.x);
            utile[4 * x + 1][ypi] = pack_h2(v0.y, v1.y);
            utile[4 * x + 2][ypi] = pack_h2(v0.z, v1.z);
            utile[4 * x + 3][ypi] = pack_h2(v0.w, v1.w);
        }
        __syncthreads();
        const int j = tid & 31, nn0 = tid >> 5;     // j: b-pair, nn0: n-row base
#pragma unroll
        for (int i = 0; i < 8; ++i) {
            const int nn = nn0 + 8 * i;
            stateTh[(size_t)(c0 + nn) * (ESN_B / 2) + (r0 >> 1) + j] = utile[nn][j];
        }
    } else if (t < NB_TS + NB_TI) {
        // inputs [512, 256] -> inputsT [256, 512] f32
        const int t2 = t - NB_TS;
        const int bx = t2 & 7, by = t2 >> 3;
        const int tx = tid & 31, ty = tid >> 5;
        const int c0 = bx * 32, r0 = by * 32;
#pragma unroll
        for (int j = ty; j < 32; j += 8)
            tile2[j][tx] = inputs[(size_t)(r0 + j) * ESN_D + c0 + tx];
        __syncthreads();
#pragma unroll
        for (int j = ty; j < 32; j += 8)
            inputsT[(size_t)(c0 + j) * ESN_B + r0 + tx] = tile2[tx][j];
    } else {
        // COO scatter; val pre-duplicated as half2{v,v}, row pre-shifted to
        // a byte offset into stateTh (row * 1024 B per row).
        const int i = (t - NB_TS - NB_TI) * 256 + tid;
        if (i < nnz) {
            const int c = wres_cols[i];
            const int p = atomicAdd(&cnt[c], 1);
            if (p < CAP) {
                const unsigned short h = __half_as_ushort(__float2half(wres_vals[i]));
                const unsigned hv2 = (unsigned)h | ((unsigned)h << 16);
                bucket[(size_t)c * CAP + p] = make_int2(wres_rows[i] << 10, (int)hv2);
            }
        }
    }
}

__global__ __launch_bounds__(512, 8) void spmm_k(const int* __restrict__ cnt,
                                                 const int2* __restrict__ bucket,
                                                 const unsigned* __restrict__ stateTh,
                                                 const float* __restrict__ inputsT,
                                                 const float* __restrict__ win_vals,
                                                 const float* __restrict__ win_bias,
                                                 const int* __restrict__ win_rows,
                                                 float* __restrict__ out) {
    const int slice = blockIdx.x & (NSL - 1);      // even/odd XCDs <-> slice
    const int tile  = blockIdx.x >> 1;
    const int c0 = tile * GS;
    const int lane = threadIdx.x & 63;
    const int w    = threadIdx.x >> 6;             // wave 0..7 owns cols 2w, 2w+1

    __shared__ int2  ebuf[GS][LCAP + 2];           // +2: prefetch overrun pad
    __shared__ int   scnt[GS];
    __shared__ int   swr[GS];
    __shared__ float sval[GS], sbias[GS];
    __shared__ float tbuf[GS][264];                // [col][b-local], 16B-aligned rows

    if (threadIdx.x < GS) {
        const int c = c0 + threadIdx.x;
        const int n = cnt[c];
        scnt[threadIdx.x]  = (n > LCAP) ? LCAP : n;
        swr[threadIdx.x]   = win_rows[c];
        sval[threadIdx.x]  = win_vals[c];
        sbias[threadIdx.x] = win_bias[c];
    }
    __syncthreads();

    // stage + zero-pad nnz lists: 1024 int2 slots, 512 threads x 2, coalesced
    // (each wave stages one column's contiguous 512 B list)
#pragma unroll
    for (int i = 0; i < 2; ++i) {
        const int idx = threadIdx.x + 512 * i;
        const int g = idx >> 6, k = idx & (LCAP - 1);
        ebuf[g][k] = (k < scnt[g]) ? bucket[(size_t)(c0 + g) * CAP + k]
                                   : make_int2(0, 0);
    }
    __syncthreads();

    const char* __restrict__ stC = (const char*)stateTh;
    const unsigned lo = ((unsigned)slice << 9) + ((unsigned)lane << 3);  // byte off in a row

    // each wave: 2 columns sequentially, exact (even-rounded) loop bounds
#pragma unroll
    for (int gg = 0; gg < 2; ++gg) {
        const int g = 2 * w + gg;
        const int c = c0 + g;
        const int kn = (scnt[g] + 1) & ~1;          // pad slot is zero-filled
        __half2 acc0 = __half2half2(__ushort_as_half(0));
        __half2 acc1 = acc0;

        int4 q = *(const int4*)&ebuf[g][0];         // prefetch (b128 broadcast)
        for (int k = 0; k < kn; k += 2) {
            const int4 qc = q;
            q = *(const int4*)&ebuf[g][k + 2];      // may touch pad slots: safe
            const uint2 s0 = *(const uint2*)(stC + (unsigned)qc.x + lo);
            const uint2 s1 = *(const uint2*)(stC + (unsigned)qc.z + lo);
            const __half2 v0 = int_as_h2(qc.y);
            const __half2 v1 = int_as_h2(qc.w);
            acc0 = __hfma2(int_as_h2((int)s0.x), v0, acc0);
            acc1 = __hfma2(int_as_h2((int)s0.y), v0, acc1);
            acc0 = __hfma2(int_as_h2((int)s1.x), v1, acc0);
            acc1 = __hfma2(int_as_h2((int)s1.y), v1, acc1);
        }

        // epilogue for col c, 4 b's/lane: b = 256*slice + 4*lane + {0,1,2,3}
        const uint2 pp = *(const uint2*)(stC + ((unsigned)c << 10) + lo);
        const float4 ii = *(const float4*)(inputsT + (size_t)swr[g] * ESN_B
                                           + (slice << 8) + 4 * lane);
        const float wv = sval[g], wb = sbias[g];
        const __half2 p0 = int_as_h2((int)pp.x), p1 = int_as_h2((int)pp.y);
        const float st0 = __low2float(p0), st1 = __high2float(p0);
        const float st2v = __low2float(p1), st3 = __high2float(p1);
        const float t0 = fast_tanh(ii.x * wv + wb + __low2float(acc0));
        const float t1 = fast_tanh(ii.y * wv + wb + __high2float(acc0));
        const float t2 = fast_tanh(ii.z * wv + wb + __low2float(acc1));
        const float t3 = fast_tanh(ii.w * wv + wb + __high2float(acc1));
        *(float4*)&tbuf[g][4 * lane] =
            make_float4(st0 + ESN_ALPHA * (t0 - st0),
                        st1 + ESN_ALPHA * (t1 - st1),
                        st2v + ESN_ALPHA * (t2 - st2v),
                        st3 + ESN_ALPHA * (t3 - st3));
    }
    __syncthreads();

    // reshuffle -> row-major out: thread pair (2b, 2b+1) writes one full
    // 64-B line (16 cols) for batch row b.
    {
        const int b = threadIdx.x >> 1;
        const int h = (threadIdx.x & 1) << 3;       // col offset 0 or 8
        const float4 o0 = make_float4(tbuf[h + 0][b], tbuf[h + 1][b],
                                      tbuf[h + 2][b], tbuf[h + 3][b]);
        const float4 o1 = make_float4(tbuf[h + 4][b], tbuf[h + 5][b],
                                      tbuf[h + 6][b], tbuf[h + 7][b]);
        float* op = out + (size_t)((slice << 8) + b) * ESN_N + c0 + h;
        *(float4*)op = o0;
        *(float4*)(op + 4) = o1;
    }
}

extern "C" void kernel_launch(void* const* d_in, const int* in_sizes, int n_in,
                              void* d_out, int out_size, void* d_ws, size_t ws_size,
                              hipStream_t stream) {
    const float* inputs    = (const float*)d_in[0];  // [B, D]
    const float* state     = (const float*)d_in[1];  // [B, N]
    const float* win_vals  = (const float*)d_in[2];  // [N]
    const float* win_bias  = (const float*)d_in[3];  // [N]
    const float* wres_vals = (const float*)d_in[4];  // [NNZ]
    const int*   win_rows  = (const int*)d_in[5];    // [N]
    const int*   wres_rows = (const int*)d_in[6];    // [NNZ]
    const int*   wres_cols = (const int*)d_in[7];    // [NNZ]
    float* out = (float*)d_out;                      // [B, N]

    const int NNZ = in_sizes[4];

    char* w = (char*)d_ws;
    unsigned* stateTh = (unsigned*)(w);                                  // 8 MB
    float*    inputsT = (float*)(w + (size_t)ESN_N * (ESN_B / 2) * 4);   // 512 KB
    int2*     bucket  = (int2*)((char*)inputsT + (size_t)ESN_D * ESN_B * 4); // 8 MB
    int*      cnt     = (int*)((char*)bucket + (size_t)ESN_N * CAP * 8); // 32 KB

    hipMemsetAsync(cnt, 0, ESN_N * sizeof(int), stream);

    const int nb_sc = (NNZ + 255) / 256;
    const int nb = (ESN_N / 64) * (ESN_B / 64) + (ESN_D / 32) * (ESN_B / 32) + nb_sc;
    prep_k<<<nb, 256, 0, stream>>>(state, inputs, wres_rows, wres_cols, wres_vals,
                                   cnt, bucket, stateTh, inputsT, NNZ);

    spmm_k<<<(ESN_N / GS) * NSL, 512, 0, stream>>>(cnt, bucket, stateTh, inputsT,
                                                   win_vals, win_bias, win_rows, out);
}